// Round 13
// baseline (676.358 us; speedup 1.0000x reference)
//
#include <hip/hip_runtime.h>
#include <stdint.h>

typedef _Float16 f16;
typedef unsigned short u16;
typedef __attribute__((ext_vector_type(8))) _Float16 h16x8;
typedef __attribute__((ext_vector_type(8))) unsigned short u16x8;
typedef __attribute__((ext_vector_type(4))) float f32x4;

#define NDIM  4096
#define KDIM  4096
#define LRDIM 64

__device__ __forceinline__ float bf2f(u16 b) {
  union { unsigned u; float f; } c; c.u = ((unsigned)b) << 16; return c.f;
}
__device__ __forceinline__ float h2f(u16 b) {
  union { u16 u; f16 h; } c; c.u = b; return (float)c.h;
}
__device__ __forceinline__ h16x8 pack8(float4 a, float4 b) {
  h16x8 w = { (f16)a.x, (f16)a.y, (f16)a.z, (f16)a.w,
              (f16)b.x, (f16)b.y, (f16)b.z, (f16)b.w };
  return w;
}

// async global->LDS, 16B/lane; true addrspacecast (proven green r10/r12).
__device__ __forceinline__ void gll16(const void* g, void* l) {
  __builtin_amdgcn_global_load_lds(
      (const __attribute__((address_space(1))) void*)g,
      (__attribute__((address_space(3))) void*)l,
      16, 0, 0);
}

// ---------------------------------------------------------------------------
// frozen encoding classifier (proven): 0=f16, 1=bf16, 2=f32 halfword layout.
// ---------------------------------------------------------------------------
__device__ int frozen_mode(const void* frozen, int t) {
  const u16* fr = (const u16*)frozen;
  __shared__ int sE[256], sO[256];
  int ce = 0, co = 0;
  for (int j = 0; j < 8; ++j) {
    float ve = fabsf(bf2f(fr[t * 16 + 2 * j]));
    float vo = fabsf(bf2f(fr[t * 16 + 2 * j + 1]));
    if (ve >= 0.05f && ve <= 10.0f) ++ce;
    if (vo >= 0.05f && vo <= 10.0f) ++co;
  }
  sE[t] = ce; sO[t] = co;
  __syncthreads();
  for (int s = 128; s > 0; s >>= 1) {
    if (t < s) { sE[t] += sE[t + s]; sO[t] += sO[t + s]; }
    __syncthreads();
  }
  int te = sE[0], to = sO[0];
  __syncthreads();
  if (to > 1024) return (te > 1024) ? 1 : 2;
  return 0;
}

__device__ __forceinline__ h16x8 build_m8(
    const void* __restrict__ frozen, const float* __restrict__ gs,
    const float* __restrict__ gb, const float* __restrict__ sa,
    int o, int i0, int mode)
{
  size_t fo = (size_t)o * KDIM + i0;
  int gidx = (o >> 3) * 512 + (i0 >> 3);
  float gsf = gs[gidx], gbf = gb[gidx];
  float4 s0 = ((const float4*)(sa + fo))[0];
  float4 s1 = ((const float4*)(sa + fo))[1];
  float sv[8] = { s0.x, s0.y, s0.z, s0.w, s1.x, s1.y, s1.z, s1.w };
  float fv[8];
  if (mode == 2) {
    float4 q0 = ((const float4*)((const float*)frozen + fo))[0];
    float4 q1 = ((const float4*)((const float*)frozen + fo))[1];
    fv[0]=q0.x; fv[1]=q0.y; fv[2]=q0.z; fv[3]=q0.w;
    fv[4]=q1.x; fv[5]=q1.y; fv[6]=q1.z; fv[7]=q1.w;
  } else {
    u16x8 fb = *(const u16x8*)((const u16*)frozen + fo);
#pragma unroll
    for (int j = 0; j < 8; ++j) fv[j] = (mode == 1) ? bf2f(fb[j]) : h2f(fb[j]);
  }
  h16x8 w;
#pragma unroll
  for (int j = 0; j < 8; ++j) w[j] = (f16)(gbf + fv[j] * gsf + sv[j]);
  return w;
}

// ---------------------------------------------------------------------------
// k9_build_m / k9_cast_x (proven, unchanged)
// ---------------------------------------------------------------------------
__global__ __launch_bounds__(256) void k9_build_m(
    const void* __restrict__ frozen, const float* __restrict__ gs,
    const float* __restrict__ gb, const float* __restrict__ sa,
    f16* __restrict__ mW)
{
  int mode = frozen_mode(frozen, threadIdx.x);
  int idx = blockIdx.x * 256 + threadIdx.x;
  int o  = idx >> 9;
  int ig = idx & 511;
  h16x8 w = build_m8(frozen, gs, gb, sa, o, ig * 8, mode);
  *(h16x8*)(mW + (size_t)o * KDIM + ig * 8) = w;
}

__global__ __launch_bounds__(256) void k9_cast_x(const float* __restrict__ x,
                                                 f16* __restrict__ xh)
{
  size_t idx = (size_t)blockIdx.x * 256 + threadIdx.x;
  const float4* xp = (const float4*)x + idx * 2;
  *(h16x8*)(xh + idx * 8) = pack8(xp[0], xp[1]);
}

// ---------------------------------------------------------------------------
// k13_hid: hid = xh @ L1^T via MFMA; A staged from f16 xh via gll16 (halves
// the dominant prep stream vs f32 x); B reg-staged from f32 L1 (proven path).
// BM=128, BN=64, BK=32, 4 waves 2x2, dbuf, 64 blocks.
// ---------------------------------------------------------------------------
__global__ __launch_bounds__(256) void k13_hid(const f16* __restrict__ xh,
                                               const float* __restrict__ L1,
                                               f16* __restrict__ hid)
{
  __shared__ f16 sA[2][128 * 32];
  __shared__ f16 sB[2][64 * 32];
  int t = threadIdx.x;
  int l = t & 63, wid = t >> 6;
  int wr = wid >> 1, wc = wid & 1;
  int brow = blockIdx.x * 128;
  int ur = t >> 2, uc8 = (t & 3) * 8;   // A units: t (rows 0-63), t+256 (64-127)
  int brw = t >> 2, bc8 = (t & 3) * 8;  // B: one 8-elem unit (64 rows)

  f32x4 acc[4][2] = {};

  {
    gll16(xh + (size_t)(brow + ur) * KDIM + uc8,      &sA[0][ur * 32 + uc8]);
    gll16(xh + (size_t)(brow + ur + 64) * KDIM + uc8, &sA[0][(ur + 64) * 32 + uc8]);
    const float* lp = L1 + (size_t)brw * KDIM + bc8;
    *(h16x8*)&sB[0][brw * 32 + bc8] = pack8(((const float4*)lp)[0], ((const float4*)lp)[1]);
  }

  int cur = 0;
  const int NT = KDIM / 32;
  for (int kt = 0; kt < NT; ++kt) {
    __syncthreads();
    bool pf = (kt + 1 < NT);
    h16x8 wb;
    if (pf) {
      int k0 = (kt + 1) * 32;
      gll16(xh + (size_t)(brow + ur) * KDIM + k0 + uc8,      &sA[cur ^ 1][ur * 32 + uc8]);
      gll16(xh + (size_t)(brow + ur + 64) * KDIM + k0 + uc8, &sA[cur ^ 1][(ur + 64) * 32 + uc8]);
      const float* lp = L1 + (size_t)brw * KDIM + k0 + bc8;
      wb = pack8(((const float4*)lp)[0], ((const float4*)lp)[1]);
    }
    h16x8 aF[4], bF[2];
#pragma unroll
    for (int m = 0; m < 4; ++m)
      aF[m] = *(const h16x8*)&sA[cur][(wr * 64 + m * 16 + (l & 15)) * 32 + (l >> 4) * 8];
#pragma unroll
    for (int n = 0; n < 2; ++n)
      bF[n] = *(const h16x8*)&sB[cur][(wc * 32 + n * 16 + (l & 15)) * 32 + (l >> 4) * 8];
#pragma unroll
    for (int m = 0; m < 4; ++m)
#pragma unroll
      for (int n = 0; n < 2; ++n)
        acc[m][n] = __builtin_amdgcn_mfma_f32_16x16x32_f16(aF[m], bF[n], acc[m][n], 0, 0, 0);
    if (pf)
      *(h16x8*)&sB[cur ^ 1][brw * 32 + bc8] = wb;
    cur ^= 1;
  }

#pragma unroll
  for (int m = 0; m < 4; ++m)
#pragma unroll
    for (int n = 0; n < 2; ++n)
#pragma unroll
      for (int j = 0; j < 4; ++j) {
        int r = wr * 64 + m * 16 + ((l >> 4) << 2) + j;
        int c = wc * 32 + n * 16 + (l & 15);
        hid[(size_t)(brow + r) * LRDIM + c] = (f16)acc[m][n][j];
      }
}

// ---------------------------------------------------------------------------
// k13_main: identical to proven k12_main except __launch_bounds__(256, 5):
// VGPR 84 <= 512/5 = 102 and LDS 32KB x 5 = exactly 160KB -> 5 blocks/CU
// target (cross-block overlap hides the per-block vmcnt(0) barrier drains).
// ---------------------------------------------------------------------------
__global__ __launch_bounds__(256, 5) void k13_main(
    const f16* __restrict__ xh, const f16* __restrict__ mW,
    const f16* __restrict__ hid, const float* __restrict__ L2,
    const float* __restrict__ scale, const float* __restrict__ bias,
    float* __restrict__ out)
{
  __shared__ f16 sA[2][128 * 32];
  __shared__ f16 sB[2][128 * 32];
  int t = threadIdx.x;
  int l = t & 63, wid = t >> 6;
  int wr = wid >> 1, wc = wid & 1;

  int wg = blockIdx.x;
  int cpx = gridDim.x >> 3;
  int swz = (wg & 7) * cpx + (wg >> 3);
  int bm = swz & 63;
  int bn = swz >> 6;
  int brow = bm * 128, bcol = bn * 128;

  int ur = t >> 2, uc8 = (t & 3) * 8;

  f32x4 acc[4][4] = {};

  // ---- prologue: stage kt = 0 (wave-linear LDS offsets) ----
  gll16(xh + (size_t)(brow + ur) * KDIM + uc8,      &sA[0][ur * 32 + uc8]);
  gll16(xh + (size_t)(brow + ur + 64) * KDIM + uc8, &sA[0][(ur + 64) * 32 + uc8]);
  gll16(mW + (size_t)(bcol + ur) * KDIM + uc8,      &sB[0][ur * 32 + uc8]);
  gll16(mW + (size_t)(bcol + ur + 64) * KDIM + uc8, &sB[0][(ur + 64) * 32 + uc8]);

  int cur = 0;
  const int NT = KDIM / 32;
  for (int kt = 0; kt < NT; ++kt) {
    __syncthreads();                    // drains vmcnt: buf[cur] ready
    if (kt + 1 < NT) {
      int k0 = (kt + 1) * 32;
      gll16(xh + (size_t)(brow + ur) * KDIM + k0 + uc8,      &sA[cur ^ 1][ur * 32 + uc8]);
      gll16(xh + (size_t)(brow + ur + 64) * KDIM + k0 + uc8, &sA[cur ^ 1][(ur + 64) * 32 + uc8]);
      gll16(mW + (size_t)(bcol + ur) * KDIM + k0 + uc8,      &sB[cur ^ 1][ur * 32 + uc8]);
      gll16(mW + (size_t)(bcol + ur + 64) * KDIM + k0 + uc8, &sB[cur ^ 1][(ur + 64) * 32 + uc8]);
    }
    h16x8 aF[4], bF[4];
#pragma unroll
    for (int m = 0; m < 4; ++m)
      aF[m] = *(const h16x8*)&sA[cur][(wr * 64 + m * 16 + (l & 15)) * 32 + (l >> 4) * 8];
#pragma unroll
    for (int n = 0; n < 4; ++n)
      bF[n] = *(const h16x8*)&sB[cur][(wc * 64 + n * 16 + (l & 15)) * 32 + (l >> 4) * 8];
#pragma unroll
    for (int m = 0; m < 4; ++m)
#pragma unroll
      for (int n = 0; n < 4; ++n)
        acc[m][n] = __builtin_amdgcn_mfma_f32_16x16x32_f16(aF[m], bF[n], acc[m][n], 0, 0, 0);
    cur ^= 1;
  }

  // ---- fused epilogue, m-sliced (r11/r12 proven, verbatim) ----
  __syncthreads();
  f16* sH = &sA[0][0];
  f16* sL = &sB[0][0];

  for (int j = 0; j < 4; ++j) {
    int u = t + j * 256;
    int r = u >> 3, c8 = (u & 7) * 8;
    *(h16x8*)&sH[r * 64 + c8] =
        *(const h16x8*)(hid + (size_t)(brow + r) * LRDIM + c8);
    const float* lp = L2 + (size_t)(bcol + r) * LRDIM + c8;
    *(h16x8*)&sL[r * 64 + c8] = pack8(((const float4*)lp)[0], ((const float4*)lp)[1]);
  }
  __syncthreads();

  float sc[4], bi[4];
#pragma unroll
  for (int n = 0; n < 4; ++n) {
    int o = bcol + wc * 64 + n * 16 + (l & 15);
    sc[n] = scale[o];
    bi[n] = bias[o];
  }

  // pass 1: mul = hid @ L2[0:4096]^T + scale ; acc <- mul * acc
  {
    h16x8 lB[4][2];
#pragma unroll
    for (int n = 0; n < 4; ++n)
#pragma unroll
      for (int kk = 0; kk < 2; ++kk)
        lB[n][kk] = *(const h16x8*)&sL[(wc * 64 + n * 16 + (l & 15)) * 64 + kk * 32 + (l >> 4) * 8];
#pragma unroll
    for (int m = 0; m < 4; ++m) {
      h16x8 hA0 = *(const h16x8*)&sH[(wr * 64 + m * 16 + (l & 15)) * 64 + (l >> 4) * 8];
      h16x8 hA1 = *(const h16x8*)&sH[(wr * 64 + m * 16 + (l & 15)) * 64 + 32 + (l >> 4) * 8];
      f32x4 mm[4];
#pragma unroll
      for (int n = 0; n < 4; ++n) {
        f32x4 mi = { sc[n], sc[n], sc[n], sc[n] };
        mm[n] = mi;
      }
#pragma unroll
      for (int n = 0; n < 4; ++n) {
        mm[n] = __builtin_amdgcn_mfma_f32_16x16x32_f16(hA0, lB[n][0], mm[n], 0, 0, 0);
        mm[n] = __builtin_amdgcn_mfma_f32_16x16x32_f16(hA1, lB[n][1], mm[n], 0, 0, 0);
      }
#pragma unroll
      for (int n = 0; n < 4; ++n)
        acc[m][n] *= mm[n];
    }
  }

  __syncthreads();
  for (int j = 0; j < 4; ++j) {
    int u = t + j * 256;
    int r = u >> 3, c8 = (u & 7) * 8;
    const float* lp = L2 + (size_t)(NDIM + bcol + r) * LRDIM + c8;
    *(h16x8*)&sL[r * 64 + c8] = pack8(((const float4*)lp)[0], ((const float4*)lp)[1]);
  }
  __syncthreads();

  // pass 2: add = hid @ L2[4096:8192]^T + bias ; out = add + acc
  {
    h16x8 lB[4][2];
#pragma unroll
    for (int n = 0; n < 4; ++n)
#pragma unroll
      for (int kk = 0; kk < 2; ++kk)
        lB[n][kk] = *(const h16x8*)&sL[(wc * 64 + n * 16 + (l & 15)) * 64 + kk * 32 + (l >> 4) * 8];
#pragma unroll
    for (int m = 0; m < 4; ++m) {
      h16x8 hA0 = *(const h16x8*)&sH[(wr * 64 + m * 16 + (l & 15)) * 64 + (l >> 4) * 8];
      h16x8 hA1 = *(const h16x8*)&sH[(wr * 64 + m * 16 + (l & 15)) * 64 + 32 + (l >> 4) * 8];
      f32x4 aa[4];
#pragma unroll
      for (int n = 0; n < 4; ++n) {
        f32x4 mi = { bi[n], bi[n], bi[n], bi[n] };
        aa[n] = mi;
      }
#pragma unroll
      for (int n = 0; n < 4; ++n) {
        aa[n] = __builtin_amdgcn_mfma_f32_16x16x32_f16(hA0, lB[n][0], aa[n], 0, 0, 0);
        aa[n] = __builtin_amdgcn_mfma_f32_16x16x32_f16(hA1, lB[n][1], aa[n], 0, 0, 0);
      }
      int rbase = brow + wr * 64 + m * 16 + ((l >> 4) << 2);
#pragma unroll
      for (int n = 0; n < 4; ++n) {
        int c = bcol + wc * 64 + n * 16 + (l & 15);
        f32x4 v = aa[n] + acc[m][n];
#pragma unroll
        for (int j = 0; j < 4; ++j)
          out[(size_t)(rbase + j) * NDIM + c] = v[j];
      }
    }
  }
}

// ---------------------------------------------------------------------------
extern "C" void kernel_launch(void* const* d_in, const int* in_sizes, int n_in,
                              void* d_out, int out_size, void* d_ws, size_t ws_size,
                              hipStream_t stream)
{
  const int SD[9] = {33554432,16777216,262144,524288,262144,262144,16777216,4096,4096};
  const int SA[9] = {4096,16777216,262144,262144,262144,524288,4096,16777216,33554432};
  bool dict = (n_in == 9), alph = (n_in == 9);
  if (n_in == 9) {
    for (int i = 0; i < 9; ++i) {
      if (in_sizes[i] != SD[i]) dict = false;
      if (in_sizes[i] != SA[i]) alph = false;
    }
  }
  if (!dict && !alph) {
    int ix = 0;
    for (int i = 0; i < n_in; ++i)
      if (in_sizes[i] == 33554432 || in_sizes[i] == 134217728) { ix = i; break; }
    dict = (ix == 0);
  }
  const float* x     = (const float*)d_in[dict ? 0 : 8];
  const void*  fr    =               d_in[1];
  const float* L1    = (const float*)d_in[dict ? 2 : 4];
  const float* L2    = (const float*)d_in[dict ? 3 : 5];
  const float* gs    = (const float*)d_in[dict ? 4 : 3];
  const float* gb    = (const float*)d_in[dict ? 5 : 2];
  const float* sa    = (const float*)d_in[dict ? 6 : 7];
  const float* scale = (const float*)d_in[dict ? 7 : 6];
  const float* bias  = (const float*)d_in[dict ? 8 : 0];
  float* out = (float*)d_out;

  const size_t MW_B = (size_t)NDIM * KDIM * 2;    // 33,554,432
  const size_t XH_B = (size_t)8192 * KDIM * 2;    // 67,108,864

  char* ws = (char*)d_ws;
  // ws_size proven >= this layout by rounds 9-12 (T2 path executed).
  f16* mW  = (f16*)ws;
  f16* xh  = (f16*)(ws + MW_B);
  f16* hid = (f16*)(ws + MW_B + XH_B);

  k9_cast_x<<<dim3(16384), dim3(256), 0, stream>>>(x, xh);
  k9_build_m<<<dim3(8192), dim3(256), 0, stream>>>(fr, gs, gb, sa, mW);
  k13_hid<<<dim3(64), dim3(256), 0, stream>>>(xh, L1, hid);
  k13_main<<<dim3(2048), dim3(256), 0, stream>>>(
      xh, mW, hid, L2, scale, bias, out);
}

// Round 14
// 530.634 us; speedup vs baseline: 1.2746x; 1.2746x over previous
//
#include <hip/hip_runtime.h>
#include <stdint.h>

typedef _Float16 f16;
typedef unsigned short u16;
typedef __attribute__((ext_vector_type(8))) _Float16 h16x8;
typedef __attribute__((ext_vector_type(8))) unsigned short u16x8;
typedef __attribute__((ext_vector_type(4))) float f32x4;

#define NDIM  4096
#define KDIM  4096
#define LRDIM 64

__device__ __forceinline__ float bf2f(u16 b) {
  union { unsigned u; float f; } c; c.u = ((unsigned)b) << 16; return c.f;
}
__device__ __forceinline__ float h2f(u16 b) {
  union { u16 u; f16 h; } c; c.u = b; return (float)c.h;
}
__device__ __forceinline__ h16x8 pack8(float4 a, float4 b) {
  h16x8 w = { (f16)a.x, (f16)a.y, (f16)a.z, (f16)a.w,
              (f16)b.x, (f16)b.y, (f16)b.z, (f16)b.w };
  return w;
}

// async global->LDS, 16B/lane; true addrspacecast (proven green r10/r12).
__device__ __forceinline__ void gll16(const void* g, void* l) {
  __builtin_amdgcn_global_load_lds(
      (const __attribute__((address_space(1))) void*)g,
      (__attribute__((address_space(3))) void*)l,
      16, 0, 0);
}

// ---------------------------------------------------------------------------
// frozen encoding classifier (proven): 0=f16, 1=bf16, 2=f32 halfword layout.
// ---------------------------------------------------------------------------
__device__ int frozen_mode(const void* frozen, int t) {
  const u16* fr = (const u16*)frozen;
  __shared__ int sE[256], sO[256];
  int ce = 0, co = 0;
  for (int j = 0; j < 8; ++j) {
    float ve = fabsf(bf2f(fr[t * 16 + 2 * j]));
    float vo = fabsf(bf2f(fr[t * 16 + 2 * j + 1]));
    if (ve >= 0.05f && ve <= 10.0f) ++ce;
    if (vo >= 0.05f && vo <= 10.0f) ++co;
  }
  sE[t] = ce; sO[t] = co;
  __syncthreads();
  for (int s = 128; s > 0; s >>= 1) {
    if (t < s) { sE[t] += sE[t + s]; sO[t] += sO[t + s]; }
    __syncthreads();
  }
  int te = sE[0], to = sO[0];
  __syncthreads();
  if (to > 1024) return (te > 1024) ? 1 : 2;
  return 0;
}

__device__ __forceinline__ h16x8 build_m8(
    const void* __restrict__ frozen, const float* __restrict__ gs,
    const float* __restrict__ gb, const float* __restrict__ sa,
    int o, int i0, int mode)
{
  size_t fo = (size_t)o * KDIM + i0;
  int gidx = (o >> 3) * 512 + (i0 >> 3);
  float gsf = gs[gidx], gbf = gb[gidx];
  float4 s0 = ((const float4*)(sa + fo))[0];
  float4 s1 = ((const float4*)(sa + fo))[1];
  float sv[8] = { s0.x, s0.y, s0.z, s0.w, s1.x, s1.y, s1.z, s1.w };
  float fv[8];
  if (mode == 2) {
    float4 q0 = ((const float4*)((const float*)frozen + fo))[0];
    float4 q1 = ((const float4*)((const float*)frozen + fo))[1];
    fv[0]=q0.x; fv[1]=q0.y; fv[2]=q0.z; fv[3]=q0.w;
    fv[4]=q1.x; fv[5]=q1.y; fv[6]=q1.z; fv[7]=q1.w;
  } else {
    u16x8 fb = *(const u16x8*)((const u16*)frozen + fo);
#pragma unroll
    for (int j = 0; j < 8; ++j) fv[j] = (mode == 1) ? bf2f(fb[j]) : h2f(fb[j]);
  }
  h16x8 w;
#pragma unroll
  for (int j = 0; j < 8; ++j) w[j] = (f16)(gbf + fv[j] * gsf + sv[j]);
  return w;
}

// ---------------------------------------------------------------------------
// k9_build_m / k9_cast_x (proven, unchanged)
// ---------------------------------------------------------------------------
__global__ __launch_bounds__(256) void k9_build_m(
    const void* __restrict__ frozen, const float* __restrict__ gs,
    const float* __restrict__ gb, const float* __restrict__ sa,
    f16* __restrict__ mW)
{
  int mode = frozen_mode(frozen, threadIdx.x);
  int idx = blockIdx.x * 256 + threadIdx.x;
  int o  = idx >> 9;
  int ig = idx & 511;
  h16x8 w = build_m8(frozen, gs, gb, sa, o, ig * 8, mode);
  *(h16x8*)(mW + (size_t)o * KDIM + ig * 8) = w;
}

__global__ __launch_bounds__(256) void k9_cast_x(const float* __restrict__ x,
                                                 f16* __restrict__ xh)
{
  size_t idx = (size_t)blockIdx.x * 256 + threadIdx.x;
  const float4* xp = (const float4*)x + idx * 2;
  *(h16x8*)(xh + idx * 8) = pack8(xp[0], xp[1]);
}

// ---------------------------------------------------------------------------
// k14_hid: hid = xh @ L1^T via MFMA. BM=32 -> 256 blocks (full-CU BW for the
// 67MB xh read, vs 64 blocks = 25% of CUs in r12/r13). Wave tile 16x32 (2x2).
// A via gll16 from f16 xh (threads 0-127 issue, wave-linear dest); B
// reg-staged from f32 L1 (1MB, L2-cached across blocks). Dbuf, BK=32.
// ---------------------------------------------------------------------------
__global__ __launch_bounds__(256) void k14_hid(const f16* __restrict__ xh,
                                               const float* __restrict__ L1,
                                               f16* __restrict__ hid)
{
  __shared__ f16 sA[2][32 * 32];    // 2 KB per buf
  __shared__ f16 sB[2][64 * 32];    // 4 KB per buf
  int t = threadIdx.x;
  int l = t & 63, wid = t >> 6;
  int wr = wid >> 1, wc = wid & 1;  // wave tile: rows wr*16, cols wc*32
  int brow = blockIdx.x * 32;
  int ar = t >> 2, ac8 = (t & 3) * 8;   // A: threads 0..127 -> rows 0..31
  int brw = t >> 2, bc8 = (t & 3) * 8;  // B: 64 rows x 32 cols, 8/thread

  f32x4 acc[2] = {};                // n = 0,1 (two 16-col fragments)

  {
    if (t < 128)
      gll16(xh + (size_t)(brow + ar) * KDIM + ac8, &sA[0][ar * 32 + ac8]);
    const float* lp = L1 + (size_t)brw * KDIM + bc8;
    *(h16x8*)&sB[0][brw * 32 + bc8] = pack8(((const float4*)lp)[0], ((const float4*)lp)[1]);
  }

  int cur = 0;
  const int NT = KDIM / 32;
  for (int kt = 0; kt < NT; ++kt) {
    __syncthreads();
    bool pf = (kt + 1 < NT);
    h16x8 wb;
    if (pf) {
      int k0 = (kt + 1) * 32;
      if (t < 128)
        gll16(xh + (size_t)(brow + ar) * KDIM + k0 + ac8, &sA[cur ^ 1][ar * 32 + ac8]);
      const float* lp = L1 + (size_t)brw * KDIM + k0 + bc8;
      wb = pack8(((const float4*)lp)[0], ((const float4*)lp)[1]);
    }
    h16x8 aF, bF[2];
    aF = *(const h16x8*)&sA[cur][(wr * 16 + (l & 15)) * 32 + (l >> 4) * 8];
#pragma unroll
    for (int n = 0; n < 2; ++n)
      bF[n] = *(const h16x8*)&sB[cur][(wc * 32 + n * 16 + (l & 15)) * 32 + (l >> 4) * 8];
#pragma unroll
    for (int n = 0; n < 2; ++n)
      acc[n] = __builtin_amdgcn_mfma_f32_16x16x32_f16(aF, bF[n], acc[n], 0, 0, 0);
    if (pf)
      *(h16x8*)&sB[cur ^ 1][brw * 32 + bc8] = wb;
    cur ^= 1;
  }

#pragma unroll
  for (int n = 0; n < 2; ++n)
#pragma unroll
    for (int j = 0; j < 4; ++j) {
      int r = wr * 16 + ((l >> 4) << 2) + j;
      int c = wc * 32 + n * 16 + (l & 15);
      hid[(size_t)(brow + r) * LRDIM + c] = (f16)acc[n][j];
    }
}

// ---------------------------------------------------------------------------
// k12_main (byte-identical revert to the proven r12 kernel, 425us):
// gll16 K-loop staging + m-sliced low-register epilogue, (256,3).
// ---------------------------------------------------------------------------
__global__ __launch_bounds__(256, 3) void k12_main(
    const f16* __restrict__ xh, const f16* __restrict__ mW,
    const f16* __restrict__ hid, const float* __restrict__ L2,
    const float* __restrict__ scale, const float* __restrict__ bias,
    float* __restrict__ out)
{
  __shared__ f16 sA[2][128 * 32];
  __shared__ f16 sB[2][128 * 32];
  int t = threadIdx.x;
  int l = t & 63, wid = t >> 6;
  int wr = wid >> 1, wc = wid & 1;

  int wg = blockIdx.x;
  int cpx = gridDim.x >> 3;
  int swz = (wg & 7) * cpx + (wg >> 3);
  int bm = swz & 63;
  int bn = swz >> 6;
  int brow = bm * 128, bcol = bn * 128;

  int ur = t >> 2, uc8 = (t & 3) * 8;

  f32x4 acc[4][4] = {};

  gll16(xh + (size_t)(brow + ur) * KDIM + uc8,      &sA[0][ur * 32 + uc8]);
  gll16(xh + (size_t)(brow + ur + 64) * KDIM + uc8, &sA[0][(ur + 64) * 32 + uc8]);
  gll16(mW + (size_t)(bcol + ur) * KDIM + uc8,      &sB[0][ur * 32 + uc8]);
  gll16(mW + (size_t)(bcol + ur + 64) * KDIM + uc8, &sB[0][(ur + 64) * 32 + uc8]);

  int cur = 0;
  const int NT = KDIM / 32;
  for (int kt = 0; kt < NT; ++kt) {
    __syncthreads();
    if (kt + 1 < NT) {
      int k0 = (kt + 1) * 32;
      gll16(xh + (size_t)(brow + ur) * KDIM + k0 + uc8,      &sA[cur ^ 1][ur * 32 + uc8]);
      gll16(xh + (size_t)(brow + ur + 64) * KDIM + k0 + uc8, &sA[cur ^ 1][(ur + 64) * 32 + uc8]);
      gll16(mW + (size_t)(bcol + ur) * KDIM + k0 + uc8,      &sB[cur ^ 1][ur * 32 + uc8]);
      gll16(mW + (size_t)(bcol + ur + 64) * KDIM + k0 + uc8, &sB[cur ^ 1][(ur + 64) * 32 + uc8]);
    }
    h16x8 aF[4], bF[4];
#pragma unroll
    for (int m = 0; m < 4; ++m)
      aF[m] = *(const h16x8*)&sA[cur][(wr * 64 + m * 16 + (l & 15)) * 32 + (l >> 4) * 8];
#pragma unroll
    for (int n = 0; n < 4; ++n)
      bF[n] = *(const h16x8*)&sB[cur][(wc * 64 + n * 16 + (l & 15)) * 32 + (l >> 4) * 8];
#pragma unroll
    for (int m = 0; m < 4; ++m)
#pragma unroll
      for (int n = 0; n < 4; ++n)
        acc[m][n] = __builtin_amdgcn_mfma_f32_16x16x32_f16(aF[m], bF[n], acc[m][n], 0, 0, 0);
    cur ^= 1;
  }

  __syncthreads();
  f16* sH = &sA[0][0];
  f16* sL = &sB[0][0];

  for (int j = 0; j < 4; ++j) {
    int u = t + j * 256;
    int r = u >> 3, c8 = (u & 7) * 8;
    *(h16x8*)&sH[r * 64 + c8] =
        *(const h16x8*)(hid + (size_t)(brow + r) * LRDIM + c8);
    const float* lp = L2 + (size_t)(bcol + r) * LRDIM + c8;
    *(h16x8*)&sL[r * 64 + c8] = pack8(((const float4*)lp)[0], ((const float4*)lp)[1]);
  }
  __syncthreads();

  float sc[4], bi[4];
#pragma unroll
  for (int n = 0; n < 4; ++n) {
    int o = bcol + wc * 64 + n * 16 + (l & 15);
    sc[n] = scale[o];
    bi[n] = bias[o];
  }

  // pass 1: mul = hid @ L2[0:4096]^T + scale ; acc <- mul * acc
  {
    h16x8 lB[4][2];
#pragma unroll
    for (int n = 0; n < 4; ++n)
#pragma unroll
      for (int kk = 0; kk < 2; ++kk)
        lB[n][kk] = *(const h16x8*)&sL[(wc * 64 + n * 16 + (l & 15)) * 64 + kk * 32 + (l >> 4) * 8];
#pragma unroll
    for (int m = 0; m < 4; ++m) {
      h16x8 hA0 = *(const h16x8*)&sH[(wr * 64 + m * 16 + (l & 15)) * 64 + (l >> 4) * 8];
      h16x8 hA1 = *(const h16x8*)&sH[(wr * 64 + m * 16 + (l & 15)) * 64 + 32 + (l >> 4) * 8];
      f32x4 mm[4];
#pragma unroll
      for (int n = 0; n < 4; ++n) {
        f32x4 mi = { sc[n], sc[n], sc[n], sc[n] };
        mm[n] = mi;
      }
#pragma unroll
      for (int n = 0; n < 4; ++n) {
        mm[n] = __builtin_amdgcn_mfma_f32_16x16x32_f16(hA0, lB[n][0], mm[n], 0, 0, 0);
        mm[n] = __builtin_amdgcn_mfma_f32_16x16x32_f16(hA1, lB[n][1], mm[n], 0, 0, 0);
      }
#pragma unroll
      for (int n = 0; n < 4; ++n)
        acc[m][n] *= mm[n];
    }
  }

  __syncthreads();
  for (int j = 0; j < 4; ++j) {
    int u = t + j * 256;
    int r = u >> 3, c8 = (u & 7) * 8;
    const float* lp = L2 + (size_t)(NDIM + bcol + r) * LRDIM + c8;
    *(h16x8*)&sL[r * 64 + c8] = pack8(((const float4*)lp)[0], ((const float4*)lp)[1]);
  }
  __syncthreads();

  // pass 2: add = hid @ L2[4096:8192]^T + bias ; out = add + acc
  {
    h16x8 lB[4][2];
#pragma unroll
    for (int n = 0; n < 4; ++n)
#pragma unroll
      for (int kk = 0; kk < 2; ++kk)
        lB[n][kk] = *(const h16x8*)&sL[(wc * 64 + n * 16 + (l & 15)) * 64 + kk * 32 + (l >> 4) * 8];
#pragma unroll
    for (int m = 0; m < 4; ++m) {
      h16x8 hA0 = *(const h16x8*)&sH[(wr * 64 + m * 16 + (l & 15)) * 64 + (l >> 4) * 8];
      h16x8 hA1 = *(const h16x8*)&sH[(wr * 64 + m * 16 + (l & 15)) * 64 + 32 + (l >> 4) * 8];
      f32x4 aa[4];
#pragma unroll
      for (int n = 0; n < 4; ++n) {
        f32x4 mi = { bi[n], bi[n], bi[n], bi[n] };
        aa[n] = mi;
      }
#pragma unroll
      for (int n = 0; n < 4; ++n) {
        aa[n] = __builtin_amdgcn_mfma_f32_16x16x32_f16(hA0, lB[n][0], aa[n], 0, 0, 0);
        aa[n] = __builtin_amdgcn_mfma_f32_16x16x32_f16(hA1, lB[n][1], aa[n], 0, 0, 0);
      }
      int rbase = brow + wr * 64 + m * 16 + ((l >> 4) << 2);
#pragma unroll
      for (int n = 0; n < 4; ++n) {
        int c = bcol + wc * 64 + n * 16 + (l & 15);
        f32x4 v = aa[n] + acc[m][n];
#pragma unroll
        for (int j = 0; j < 4; ++j)
          out[(size_t)(rbase + j) * NDIM + c] = v[j];
      }
    }
  }
}

// ---------------------------------------------------------------------------
extern "C" void kernel_launch(void* const* d_in, const int* in_sizes, int n_in,
                              void* d_out, int out_size, void* d_ws, size_t ws_size,
                              hipStream_t stream)
{
  const int SD[9] = {33554432,16777216,262144,524288,262144,262144,16777216,4096,4096};
  const int SA[9] = {4096,16777216,262144,262144,262144,524288,4096,16777216,33554432};
  bool dict = (n_in == 9), alph = (n_in == 9);
  if (n_in == 9) {
    for (int i = 0; i < 9; ++i) {
      if (in_sizes[i] != SD[i]) dict = false;
      if (in_sizes[i] != SA[i]) alph = false;
    }
  }
  if (!dict && !alph) {
    int ix = 0;
    for (int i = 0; i < n_in; ++i)
      if (in_sizes[i] == 33554432 || in_sizes[i] == 134217728) { ix = i; break; }
    dict = (ix == 0);
  }
  const float* x     = (const float*)d_in[dict ? 0 : 8];
  const void*  fr    =               d_in[1];
  const float* L1    = (const float*)d_in[dict ? 2 : 4];
  const float* L2    = (const float*)d_in[dict ? 3 : 5];
  const float* gs    = (const float*)d_in[dict ? 4 : 3];
  const float* gb    = (const float*)d_in[dict ? 5 : 2];
  const float* sa    = (const float*)d_in[dict ? 6 : 7];
  const float* scale = (const float*)d_in[dict ? 7 : 6];
  const float* bias  = (const float*)d_in[dict ? 8 : 0];
  float* out = (float*)d_out;

  const size_t MW_B = (size_t)NDIM * KDIM * 2;    // 33,554,432
  const size_t XH_B = (size_t)8192 * KDIM * 2;    // 67,108,864

  char* ws = (char*)d_ws;
  // ws_size proven >= this layout by rounds 9-13 (T2 path executed).
  f16* mW  = (f16*)ws;
  f16* xh  = (f16*)(ws + MW_B);
  f16* hid = (f16*)(ws + MW_B + XH_B);

  k9_cast_x<<<dim3(16384), dim3(256), 0, stream>>>(x, xh);
  k9_build_m<<<dim3(8192), dim3(256), 0, stream>>>(fr, gs, gb, sa, mW);
  k14_hid<<<dim3(256), dim3(256), 0, stream>>>(xh, L1, hid);
  k12_main<<<dim3(2048), dim3(256), 0, stream>>>(
      xh, mW, hid, L2, scale, bias, out);
}